// Round 12
// baseline (232.902 us; speedup 1.0000x reference)
//
#include <hip/hip_runtime.h>
#include <math.h>

#define LNUM 3
#define ENUM 8
#define TOPK 2
#define BSZ 256
#define NSZ 1024
#define DSZ 512
#define SSZ 128   // DS

typedef float f32x4 __attribute__((ext_vector_type(4)));

__device__ __forceinline__ f32x4 shfl_xor4(f32x4 v, int mask) {
    f32x4 r;
    r.x = __shfl_xor(v.x, mask, 64);
    r.y = __shfl_xor(v.y, mask, 64);
    r.z = __shfl_xor(v.z, mask, 64);
    r.w = __shfl_xor(v.w, mask, 64);
    return r;
}

// ---------------- mega kernel: 3 layers + q + logits, block b owns token b ----------------
// grid = BSZ blocks, 1024 threads (16 waves). All matvec reductions use in-wave
// shfl_xor K-splits (K-chunk index in LOW lane bits) -> only 4 barriers/layer.
__global__ __launch_bounds__(1024, 2) void mega_kernel(
    const float* __restrict__ token,   // [B][D]
    const float* __restrict__ node_emb,// [B][N][D]
    const float* __restrict__ states,  // [L][E][B][DS]
    const float* __restrict__ Wg,      // [L][D][E]
    const float* __restrict__ bg,      // [L][E]
    const float* __restrict__ A,       // [L][E][DS]
    const float* __restrict__ Bin,     // [L][E][D][DS]
    const float* __restrict__ Cout,    // [L][E][DS][D]
    const float* __restrict__ Dsk,     // [L][E][D]
    const float* __restrict__ Wq,      // [D][D]
    const float* __restrict__ bq,      // [D]
    float* __restrict__ out_logits,    // [B][N]
    float* __restrict__ out_states,    // [L][E][B][DS]
    float* __restrict__ acc)           // [L][2][E] (probs, sel) — pre-zeroed
{
    const int b = blockIdx.x;
    const int t = threadIdx.x;
    const int wave = t >> 6;
    const int lane = t & 63;

    __shared__ float h_s[DSZ];
    __shared__ float q_s[DSZ];
    __shared__ float snew_s[TOPK][SSZ];
    __shared__ float ypart[TOPK][DSZ];
    __shared__ float logit_s[ENUM];

    if (t < DSZ) h_s[t] = token[b * DSZ + t];

    for (int l = 0; l < LNUM; ++l) {
        const float* Wg_l  = Wg  + (size_t)l * DSZ * ENUM;
        const float* bg_l  = bg  + (size_t)l * ENUM;
        const float* A_l   = A   + (size_t)l * ENUM * SSZ;
        const float* Bin_l = Bin + (size_t)l * ENUM * DSZ * SSZ;
        const float* Cou_l = Cout+ (size_t)l * ENUM * SSZ * DSZ;
        const float* Dsk_l = Dsk + (size_t)l * ENUM * DSZ;
        const float* st_l  = states     + (size_t)l * ENUM * BSZ * SSZ;
        float*       os_l  = out_states + (size_t)l * ENUM * BSZ * SSZ;

        __syncthreads();                       // A: h_s ready
        // gating: wave w (0..7) computes expert w's logit (Wg is 16KB, L2-hot)
        if (wave < ENUM) {
            float p = 0.f;
            #pragma unroll
            for (int i = 0; i < 8; ++i) {
                const int d = lane + i * 64;
                p = fmaf(h_s[d], Wg_l[d * ENUM + wave], p);
            }
            for (int off = 32; off; off >>= 1) p += __shfl_down(p, off, 64);
            if (lane == 0) logit_s[wave] = p + bg_l[wave];
        }
        __syncthreads();                       // B: logit_s ready

        // softmax + top2, redundantly per thread (identical results)
        float probs[ENUM];
        float mx = logit_s[0];
        for (int e = 1; e < ENUM; ++e) mx = fmaxf(mx, logit_s[e]);
        float ssum = 0.f;
        for (int e = 0; e < ENUM; ++e) { probs[e] = expf(logit_s[e] - mx); ssum += probs[e]; }
        const float sinv = 1.f / ssum;
        for (int e = 0; e < ENUM; ++e) probs[e] *= sinv;

        int i0 = 0;
        for (int e = 1; e < ENUM; ++e) if (probs[e] > probs[i0]) i0 = e;
        int i1 = -1;
        for (int e = 0; e < ENUM; ++e) {
            if (e == i0) continue;
            if (i1 < 0 || probs[e] > probs[i1]) i1 = e;
        }
        float g0 = probs[i0], g1 = probs[i1];
        const float ginv = 1.f / (g0 + g1);
        g0 *= ginv; g1 *= ginv;

        if (t < ENUM) {
            atomicAdd(&acc[(l * 2 + 0) * ENUM + t], probs[t]);
            atomicAdd(&acc[(l * 2 + 1) * ENUM + t], (t == i0 || t == i1) ? 1.0f : 0.0f);
        }

        // ---- s_new: both experts; t -> (k = t>>9, sq = (t&511)>>4, kc = t&15) ----
        {
            const int k  = t >> 9;
            const int r  = t & 511;
            const int sq = r >> 4;             // 0..31 column quad
            const int kc = r & 15;             // K-chunk of 32 rows (in-wave!)
            const int e  = k ? i1 : i0;
            const float* Bp = Bin_l + (size_t)e * DSZ * SSZ + (size_t)(kc * 32) * SSZ + sq * 4;
            const float* hp = h_s + kc * 32;
            f32x4 a0 = {0.f,0.f,0.f,0.f}, a1 = a0;
            #pragma unroll 4
            for (int d = 0; d < 32; d += 2) {
                a0 += *(const f32x4*)(Bp + (size_t)d * SSZ) * hp[d];
                a1 += *(const f32x4*)(Bp + (size_t)(d + 1) * SSZ) * hp[d + 1];
            }
            f32x4 s4 = a0 + a1;
            s4 += shfl_xor4(s4, 1);
            s4 += shfl_xor4(s4, 2);
            s4 += shfl_xor4(s4, 4);
            s4 += shfl_xor4(s4, 8);
            if (kc < 4) {                      // lane kc finalizes element kc
                const int s = sq * 4 + kc;
                const float sum = (kc == 0) ? s4.x : (kc == 1) ? s4.y : (kc == 2) ? s4.z : s4.w;
                const float a = A_l[e * SSZ + s];
                const float decay = 1.f / (1.f + expf(-a));
                const float sn = decay * st_l[((size_t)e * BSZ + b) * SSZ + s] + sum;
                snew_s[k][s] = sn;
                os_l[((size_t)e * BSZ + b) * SSZ + s] = sn;
            }
        }
        // passthrough out_states for unselected experts (same phase, no barrier dep)
        {
            const int e = t >> 7, s = t & 127;
            if (e != i0 && e != i1)
                os_l[((size_t)e * BSZ + b) * SSZ + s] = st_l[((size_t)e * BSZ + b) * SSZ + s];
        }
        __syncthreads();                       // C: snew_s ready

        // ---- y: both experts; t -> (k = t>>9, dq = (t&511)>>2, sc = t&3) ----
        {
            const int k  = t >> 9;
            const int r  = t & 511;
            const int dq = r >> 2;             // 0..127 output quad
            const int sc = r & 3;              // S-chunk of 32 (in-wave)
            const int e  = k ? i1 : i0;
            const float* Cp = Cou_l + (size_t)e * SSZ * DSZ + (size_t)(sc * 32) * DSZ + dq * 4;
            const float* sp = snew_s[k] + sc * 32;
            f32x4 a0 = {0.f,0.f,0.f,0.f}, a1 = a0;
            #pragma unroll 4
            for (int s = 0; s < 32; s += 2) {
                a0 += *(const f32x4*)(Cp + (size_t)s * DSZ) * sp[s];
                a1 += *(const f32x4*)(Cp + (size_t)(s + 1) * DSZ) * sp[s + 1];
            }
            f32x4 s4 = a0 + a1;
            s4 += shfl_xor4(s4, 1);
            s4 += shfl_xor4(s4, 2);
            const float yv = (sc == 0) ? s4.x : (sc == 1) ? s4.y : (sc == 2) ? s4.z : s4.w;
            ypart[k][dq * 4 + sc] = yv;        // consecutive lanes -> consecutive floats
        }
        __syncthreads();                       // D: ypart ready

        // h update (writes h_s; next layer's barrier A fences it)
        if (t < DSZ) {
            const float hd = h_s[t];
            const float y0 = ypart[0][t] + hd * Dsk_l[i0 * DSZ + t];
            const float y1 = ypart[1][t] + hd * Dsk_l[i1 * DSZ + t];
            h_s[t] = hd + g0 * y0 + g1 * y1;
        }
    }

    __syncthreads();                           // h_s final ready
    // ---- q = h @ Wq + bq: t -> (dq = t>>3, kc = t&7) ----
    {
        const int dq = t >> 3, kc = t & 7;
        const float* Wp = Wq + (size_t)(kc * 64) * DSZ + dq * 4;
        const float* hp = h_s + kc * 64;
        f32x4 a0 = {0.f,0.f,0.f,0.f}, a1 = a0;
        #pragma unroll 4
        for (int i = 0; i < 64; i += 2) {
            a0 += *(const f32x4*)(Wp + (size_t)i * DSZ) * hp[i];
            a1 += *(const f32x4*)(Wp + (size_t)(i + 1) * DSZ) * hp[i + 1];
        }
        f32x4 s4 = a0 + a1;
        s4 += shfl_xor4(s4, 1);
        s4 += shfl_xor4(s4, 2);
        s4 += shfl_xor4(s4, 4);
        if (kc < 4) {
            const int d = dq * 4 + kc;
            q_s[d] = ((kc == 0) ? s4.x : (kc == 1) ? s4.y : (kc == 2) ? s4.z : s4.w) + bq[d];
        }
    }
    __syncthreads();                           // q_s ready

    // ---- logits: wave w streams rows w*64 .. w*64+63 of node_emb[b] ----
    {
        const f32x4 q0 = ((const f32x4*)q_s)[lane];
        const f32x4 q1 = ((const f32x4*)q_s)[lane + 64];
        const float scale = 0.04419417382415922f;  // 1/sqrt(512)
        const int n0 = wave * 64;
        for (int i = 0; i < 64; i += 2) {
            const f32x4* r0 = (const f32x4*)(node_emb + ((size_t)b * NSZ + n0 + i) * DSZ);
            const f32x4* r1 = (const f32x4*)(node_emb + ((size_t)b * NSZ + n0 + i + 1) * DSZ);
            const f32x4 a0 = __builtin_nontemporal_load(r0 + lane);
            const f32x4 a1 = __builtin_nontemporal_load(r0 + lane + 64);
            const f32x4 c0 = __builtin_nontemporal_load(r1 + lane);
            const f32x4 c1 = __builtin_nontemporal_load(r1 + lane + 64);
            float d0 = a0.x*q0.x + a0.y*q0.y + a0.z*q0.z + a0.w*q0.w
                     + a1.x*q1.x + a1.y*q1.y + a1.z*q1.z + a1.w*q1.w;
            float d1 = c0.x*q0.x + c0.y*q0.y + c0.z*q0.z + c0.w*q0.w
                     + c1.x*q1.x + c1.y*q1.y + c1.z*q1.z + c1.w*q1.w;
            #pragma unroll
            for (int off = 32; off; off >>= 1) {
                d0 += __shfl_down(d0, off, 64);
                d1 += __shfl_down(d1, off, 64);
            }
            if (lane == 0) {
                out_logits[b * NSZ + n0 + i]     = d0 * scale;
                out_logits[b * NSZ + n0 + i + 1] = d1 * scale;
            }
        }
    }
}

// ---------------- lb_loss finisher ----------------
__global__ void loss_kernel(const float* __restrict__ acc, float* __restrict__ out)
{
    if (threadIdx.x == 0) {
        float lb = 0.f;
        for (int l = 0; l < LNUM; ++l)
            for (int e = 0; e < ENUM; ++e) {
                const float mp = acc[(l * 2 + 0) * ENUM + e] * (1.0f / BSZ);
                const float ms = acc[(l * 2 + 1) * ENUM + e] * (1.0f / BSZ);
                lb += (float)ENUM * mp * ms;
            }
        out[0] = lb;
    }
}

extern "C" void kernel_launch(void* const* d_in, const int* in_sizes, int n_in,
                              void* d_out, int out_size, void* d_ws, size_t ws_size,
                              hipStream_t stream) {
    const float* token    = (const float*)d_in[0];  // B,1,D
    const float* node_emb = (const float*)d_in[1];  // B,N,D
    const float* states   = (const float*)d_in[2];  // L,E,B,DS
    const float* Wg       = (const float*)d_in[3];  // L,D,E
    const float* bg       = (const float*)d_in[4];  // L,E
    const float* A        = (const float*)d_in[5];  // L,E,DS
    const float* Bin      = (const float*)d_in[6];  // L,E,D,DS
    const float* Cout     = (const float*)d_in[7];  // L,E,DS,D
    const float* Dsk      = (const float*)d_in[8];  // L,E,D
    const float* Wq       = (const float*)d_in[9];  // D,D
    const float* bq       = (const float*)d_in[10]; // D

    float* out_logits = (float*)d_out;                                  // B*N
    float* out_states = out_logits + (size_t)BSZ * NSZ;                 // L*E*B*DS
    float* out_loss   = out_states + (size_t)LNUM * ENUM * BSZ * SSZ;   // 1

    float* ws_acc = (float*)d_ws;   // 48 floats

    (void)hipMemsetAsync(ws_acc, 0, sizeof(float) * LNUM * 16, stream);

    mega_kernel<<<BSZ, 1024, 0, stream>>>(
        token, node_emb, states, Wg, bg, A, Bin, Cout, Dsk, Wq, bq,
        out_logits, out_states, ws_acc);

    loss_kernel<<<1, 64, 0, stream>>>(ws_acc, out_loss);
}

// Round 13
// 170.685 us; speedup vs baseline: 1.3645x; 1.3645x over previous
//
#include <hip/hip_runtime.h>
#include <math.h>

#define LNUM 3
#define ENUM 8
#define TOPK 2
#define BSZ 256
#define NSZ 1024
#define DSZ 512
#define SSZ 128   // DS

typedef float f32x4 __attribute__((ext_vector_type(4)));

// ---------------- mega kernel: 3 layers + q + logits, block b owns token b ----------------
// grid = BSZ blocks, 1024 threads (16 waves). h lives in LDS across layers;
// q never leaves LDS; each block streams its own node_emb slice for logits.
// Experts processed sequentially (R10 result: -8us vs concurrent).
// LDS-partial combines keep column index in LOW lane bits => coalesced loads
// (R12 result: in-wave shfl K-split destroys coalescing, +72us).
__global__ __launch_bounds__(1024, 2) void mega_kernel(
    const float* __restrict__ token,   // [B][D]
    const float* __restrict__ node_emb,// [B][N][D]
    const float* __restrict__ states,  // [L][E][B][DS]
    const float* __restrict__ Wg,      // [L][D][E]
    const float* __restrict__ bg,      // [L][E]
    const float* __restrict__ A,       // [L][E][DS]
    const float* __restrict__ Bin,     // [L][E][D][DS]
    const float* __restrict__ Cout,    // [L][E][DS][D]
    const float* __restrict__ Dsk,     // [L][E][D]
    const float* __restrict__ Wq,      // [D][D]
    const float* __restrict__ bq,      // [D]
    float* __restrict__ out_logits,    // [B][N]
    float* __restrict__ out_states,    // [L][E][B][DS]
    float* __restrict__ acc)           // [L][2][E] (probs, sel) — pre-zeroed
{
    const int b = blockIdx.x;
    const int t = threadIdx.x;
    const int wave = t >> 6;
    const int lane = t & 63;

    __shared__ float h_s[DSZ];
    __shared__ float yacc_s[DSZ];      // also q_s in the logits phase
    __shared__ float snew_s[TOPK][SSZ];
    __shared__ float logit_s[ENUM];
    __shared__ f32x4 part4[1024];      // 16 KB scratch, reused every phase
    float* part = (float*)part4;

    if (t < 128) ((f32x4*)h_s)[t] = ((const f32x4*)(token + (size_t)b * DSZ))[t];

    for (int l = 0; l < LNUM; ++l) {
        const float* Wg_l  = Wg  + (size_t)l * DSZ * ENUM;
        const float* bg_l  = bg  + (size_t)l * ENUM;
        const float* A_l   = A   + (size_t)l * ENUM * SSZ;
        const float* Bin_l = Bin + (size_t)l * ENUM * DSZ * SSZ;
        const float* Cou_l = Cout+ (size_t)l * ENUM * SSZ * DSZ;
        const float* Dsk_l = Dsk + (size_t)l * ENUM * DSZ;
        const float* st_l  = states     + (size_t)l * ENUM * BSZ * SSZ;
        float*       os_l  = out_states + (size_t)l * ENUM * BSZ * SSZ;

        __syncthreads();   // h_s ready (init load or previous layer's update)

        // gating logits: wave w computes expert w, reading Wg directly (L2-hot)
        if (wave < ENUM) {
            float p = 0.f;
            #pragma unroll
            for (int i = 0; i < 8; ++i) {
                const int d = lane + i * 64;
                p = fmaf(h_s[d], Wg_l[d * ENUM + wave], p);
            }
            for (int off = 32; off; off >>= 1) p += __shfl_down(p, off, 64);
            if (lane == 0) logit_s[wave] = p + bg_l[wave];
        }
        __syncthreads();

        // softmax + top2, redundantly per thread (identical results)
        float probs[ENUM];
        float mx = logit_s[0];
        for (int e = 1; e < ENUM; ++e) mx = fmaxf(mx, logit_s[e]);
        float ssum = 0.f;
        for (int e = 0; e < ENUM; ++e) { probs[e] = expf(logit_s[e] - mx); ssum += probs[e]; }
        const float sinv = 1.f / ssum;
        for (int e = 0; e < ENUM; ++e) probs[e] *= sinv;

        int i0 = 0;
        for (int e = 1; e < ENUM; ++e) if (probs[e] > probs[i0]) i0 = e;
        int i1 = -1;
        for (int e = 0; e < ENUM; ++e) {
            if (e == i0) continue;
            if (i1 < 0 || probs[e] > probs[i1]) i1 = e;
        }
        float g0 = probs[i0], g1 = probs[i1];
        const float ginv = 1.f / (g0 + g1);
        g0 *= ginv; g1 *= ginv;

        if (t < ENUM) {
            atomicAdd(&acc[(l * 2 + 0) * ENUM + t], probs[t]);
            atomicAdd(&acc[(l * 2 + 1) * ENUM + t], (t == i0 || t == i1) ? 1.0f : 0.0f);
        }

        // ---- s_new: experts sequentially, all 1024 threads each ----
        #pragma unroll
        for (int k = 0; k < TOPK; ++k) {
            const int e = k ? i1 : i0;
            {
                const int c  = t >> 5;     // 0..31, K-chunk of 16 (HIGH bits)
                const int sq = t & 31;     // s-quad (LOW bits -> coalesced)
                const float* Bp = Bin_l + (size_t)e * DSZ * SSZ + sq * 4;
                const int d0 = c * 16;
                f32x4 acc4 = {0.f, 0.f, 0.f, 0.f};
                #pragma unroll
                for (int d = 0; d < 16; ++d)
                    acc4 += *(const f32x4*)(Bp + (size_t)(d0 + d) * SSZ) * h_s[d0 + d];
                part4[c * 32 + sq] = acc4;
            }
            __syncthreads();
            if (t < SSZ) {
                float sum = 0.f;
                #pragma unroll
                for (int c = 0; c < 32; ++c) sum += part[c * 128 + t];
                const float a = A_l[e * SSZ + t];
                const float decay = 1.f / (1.f + expf(-a));
                snew_s[k][t] = decay * st_l[((size_t)e * BSZ + b) * SSZ + t] + sum;
            }
            __syncthreads();
        }

        // write new_states for all 8 experts (1 elem/thread)
        {
            const int e = t >> 7, s = t & 127;
            float v;
            if (e == i0)      v = snew_s[0][s];
            else if (e == i1) v = snew_s[1][s];
            else              v = st_l[((size_t)e * BSZ + b) * SSZ + s];
            os_l[((size_t)e * BSZ + b) * SSZ + s] = v;
        }

        // ---- y: experts sequentially, all 1024 threads each ----
        #pragma unroll
        for (int k = 0; k < TOPK; ++k) {
            const int e = k ? i1 : i0;
            const float g = k ? g1 : g0;
            {
                const int sc = t >> 7;     // 0..7, S-chunk of 16 (HIGH bits)
                const int dq = t & 127;    // d-quad (LOW bits -> coalesced)
                const float* Cp = Cou_l + (size_t)e * SSZ * DSZ + dq * 4;
                const float* sp = snew_s[k];
                const int s0 = sc * 16;
                f32x4 acc4 = {0.f, 0.f, 0.f, 0.f};
                #pragma unroll
                for (int s = 0; s < 16; ++s)
                    acc4 += *(const f32x4*)(Cp + (size_t)(s0 + s) * DSZ) * sp[s0 + s];
                part4[sc * 128 + dq] = acc4;
            }
            __syncthreads();
            if (t < DSZ) {
                float yk = 0.f;
                #pragma unroll
                for (int sc = 0; sc < 8; ++sc) yk += part[sc * 512 + t];
                const float hd = h_s[t];
                yk = g * (yk + hd * Dsk_l[e * DSZ + t]);
                if (k == 0) yacc_s[t] = yk;
                else        h_s[t] = hd + yacc_s[t] + yk;
            }
            __syncthreads();
        }
    }

    // ---- q = h @ Wq + bq -> yacc_s (stays in LDS) ----
    {
        const int chunk = t >> 7;        // 0..7, dd-chunk of 64
        const int dquad = t & 127;
        const int dd0 = chunk * 64;
        f32x4 acc4 = {0.f, 0.f, 0.f, 0.f};
        #pragma unroll 8
        for (int i = 0; i < 64; ++i)
            acc4 += *(const f32x4*)(Wq + (size_t)(dd0 + i) * DSZ + dquad * 4) * h_s[dd0 + i];
        part4[chunk * 128 + dquad] = acc4;
    }
    __syncthreads();
    if (t < DSZ) {
        float qv = bq[t];
        #pragma unroll
        for (int c = 0; c < 8; ++c) qv += part[c * 512 + t];
        yacc_s[t] = qv;
    }
    __syncthreads();

    // ---- logits: wave w streams rows w*64 .. w*64+63 of node_emb[b] ----
    {
        const f32x4 q0 = ((const f32x4*)yacc_s)[lane];
        const f32x4 q1 = ((const f32x4*)yacc_s)[lane + 64];
        const float scale = 0.04419417382415922f;  // 1/sqrt(512)
        const int n0 = wave * 64;
        for (int i = 0; i < 64; i += 2) {
            const f32x4* r0 = (const f32x4*)(node_emb + ((size_t)b * NSZ + n0 + i) * DSZ);
            const f32x4* r1 = (const f32x4*)(node_emb + ((size_t)b * NSZ + n0 + i + 1) * DSZ);
            const f32x4 a0 = __builtin_nontemporal_load(r0 + lane);
            const f32x4 a1 = __builtin_nontemporal_load(r0 + lane + 64);
            const f32x4 c0 = __builtin_nontemporal_load(r1 + lane);
            const f32x4 c1 = __builtin_nontemporal_load(r1 + lane + 64);
            float d0 = a0.x*q0.x + a0.y*q0.y + a0.z*q0.z + a0.w*q0.w
                     + a1.x*q1.x + a1.y*q1.y + a1.z*q1.z + a1.w*q1.w;
            float d1 = c0.x*q0.x + c0.y*q0.y + c0.z*q0.z + c0.w*q0.w
                     + c1.x*q1.x + c1.y*q1.y + c1.z*q1.z + c1.w*q1.w;
            #pragma unroll
            for (int off = 32; off; off >>= 1) {
                d0 += __shfl_down(d0, off, 64);
                d1 += __shfl_down(d1, off, 64);
            }
            if (lane == 0) {
                out_logits[b * NSZ + n0 + i]     = d0 * scale;
                out_logits[b * NSZ + n0 + i + 1] = d1 * scale;
            }
        }
    }
}

// ---------------- lb_loss finisher ----------------
__global__ void loss_kernel(const float* __restrict__ acc, float* __restrict__ out)
{
    if (threadIdx.x == 0) {
        float lb = 0.f;
        for (int l = 0; l < LNUM; ++l)
            for (int e = 0; e < ENUM; ++e) {
                const float mp = acc[(l * 2 + 0) * ENUM + e] * (1.0f / BSZ);
                const float ms = acc[(l * 2 + 1) * ENUM + e] * (1.0f / BSZ);
                lb += (float)ENUM * mp * ms;
            }
        out[0] = lb;
    }
}

extern "C" void kernel_launch(void* const* d_in, const int* in_sizes, int n_in,
                              void* d_out, int out_size, void* d_ws, size_t ws_size,
                              hipStream_t stream) {
    const float* token    = (const float*)d_in[0];  // B,1,D
    const float* node_emb = (const float*)d_in[1];  // B,N,D
    const float* states   = (const float*)d_in[2];  // L,E,B,DS
    const float* Wg       = (const float*)d_in[3];  // L,D,E
    const float* bg       = (const float*)d_in[4];  // L,E
    const float* A        = (const float*)d_in[5];  // L,E,DS
    const float* Bin      = (const float*)d_in[6];  // L,E,D,DS
    const float* Cout     = (const float*)d_in[7];  // L,E,DS,D
    const float* Dsk      = (const float*)d_in[8];  // L,E,D
    const float* Wq       = (const float*)d_in[9];  // D,D
    const float* bq       = (const float*)d_in[10]; // D

    float* out_logits = (float*)d_out;                                  // B*N
    float* out_states = out_logits + (size_t)BSZ * NSZ;                 // L*E*B*DS
    float* out_loss   = out_states + (size_t)LNUM * ENUM * BSZ * SSZ;   // 1

    float* ws_acc = (float*)d_ws;   // 48 floats

    (void)hipMemsetAsync(ws_acc, 0, sizeof(float) * LNUM * 16, stream);

    mega_kernel<<<BSZ, 1024, 0, stream>>>(
        token, node_emb, states, Wg, bg, A, Bin, Cout, Dsk, Wq, bq,
        out_logits, out_states, ws_acc);

    loss_kernel<<<1, 64, 0, stream>>>(ws_acc, out_loss);
}

// Round 14
// 166.341 us; speedup vs baseline: 1.4001x; 1.0261x over previous
//
#include <hip/hip_runtime.h>
#include <math.h>

#define LNUM 3
#define ENUM 8
#define TOPK 2
#define BSZ 256
#define NSZ 1024
#define DSZ 512
#define SSZ 128   // DS

typedef float f32x4 __attribute__((ext_vector_type(4)));

// ---------------- mega kernel: 3 layers + q + logits, block b owns token b ----------------
// grid = BSZ blocks, 1024 threads (16 waves). h lives in LDS across layers;
// q never leaves LDS; each block streams its own node_emb slice for logits.
// Experts processed CONCURRENTLY (expert slot in bit 9, col idx in low bits ->
// coalesced; R12 showed K-in-low-bits destroys coalescing). 7 barriers/layer.
__global__ __launch_bounds__(1024, 2) void mega_kernel(
    const float* __restrict__ token,   // [B][D]
    const float* __restrict__ node_emb,// [B][N][D]
    const float* __restrict__ states,  // [L][E][B][DS]
    const float* __restrict__ Wg,      // [L][D][E]
    const float* __restrict__ bg,      // [L][E]
    const float* __restrict__ A,       // [L][E][DS]
    const float* __restrict__ Bin,     // [L][E][D][DS]
    const float* __restrict__ Cout,    // [L][E][DS][D]
    const float* __restrict__ Dsk,     // [L][E][D]
    const float* __restrict__ Wq,      // [D][D]
    const float* __restrict__ bq,      // [D]
    float* __restrict__ out_logits,    // [B][N]
    float* __restrict__ out_states,    // [L][E][B][DS]
    float* __restrict__ acc)           // [L][2][E] (probs, sel) — pre-zeroed
{
    const int b = blockIdx.x;
    const int t = threadIdx.x;
    const int wave = t >> 6;
    const int lane = t & 63;
    const int ehalf = t >> 9;          // 0/1: expert slot for matvec phases

    __shared__ float h_s[DSZ];
    __shared__ float q_s[DSZ];
    __shared__ float snew_s[TOPK][SSZ];
    __shared__ float logit_s[ENUM];
    __shared__ f32x4 part4[1024];      // 16 KB scratch, reused every phase
    float* part = (float*)part4;

    if (t < 128) ((f32x4*)h_s)[t] = ((const f32x4*)(token + (size_t)b * DSZ))[t];

    for (int l = 0; l < LNUM; ++l) {
        const float* Wg_l  = Wg  + (size_t)l * DSZ * ENUM;
        const float* bg_l  = bg  + (size_t)l * ENUM;
        const float* A_l   = A   + (size_t)l * ENUM * SSZ;
        const float* Bin_l = Bin + (size_t)l * ENUM * DSZ * SSZ;
        const float* Cou_l = Cout+ (size_t)l * ENUM * SSZ * DSZ;
        const float* Dsk_l = Dsk + (size_t)l * ENUM * DSZ;
        const float* st_l  = states     + (size_t)l * ENUM * BSZ * SSZ;
        float*       os_l  = out_states + (size_t)l * ENUM * BSZ * SSZ;

        // stage Wg[l] (16 KB) into part; also fences h_s (init load / l-1 update)
        __syncthreads();                                        // b1
        part4[t] = ((const f32x4*)Wg_l)[t];
        __syncthreads();                                        // b2

        // gating logits: wave w computes expert w from staged Wg
        if (wave < ENUM) {
            float p = 0.f;
            #pragma unroll
            for (int i = 0; i < 8; ++i) {
                const int d = lane + i * 64;
                p = fmaf(h_s[d], part[d * ENUM + wave], p);
            }
            for (int off = 32; off; off >>= 1) p += __shfl_down(p, off, 64);
            if (lane == 0) logit_s[wave] = p + bg_l[wave];
        }
        __syncthreads();                                        // b3

        // softmax + top2, redundantly per thread (identical results)
        float probs[ENUM];
        float mx = logit_s[0];
        for (int e = 1; e < ENUM; ++e) mx = fmaxf(mx, logit_s[e]);
        float ssum = 0.f;
        for (int e = 0; e < ENUM; ++e) { probs[e] = expf(logit_s[e] - mx); ssum += probs[e]; }
        const float sinv = 1.f / ssum;
        for (int e = 0; e < ENUM; ++e) probs[e] *= sinv;

        int i0 = 0;
        for (int e = 1; e < ENUM; ++e) if (probs[e] > probs[i0]) i0 = e;
        int i1 = -1;
        for (int e = 0; e < ENUM; ++e) {
            if (e == i0) continue;
            if (i1 < 0 || probs[e] > probs[i1]) i1 = e;
        }
        float g0 = probs[i0], g1 = probs[i1];
        const float ginv = 1.f / (g0 + g1);
        g0 *= ginv; g1 *= ginv;

        if (t < ENUM) {
            atomicAdd(&acc[(l * 2 + 0) * ENUM + t], probs[t]);
            atomicAdd(&acc[(l * 2 + 1) * ENUM + t], (t == i0 || t == i1) ? 1.0f : 0.0f);
        }
        const int esel = ehalf ? i1 : i0;

        // ---- s_new partials, both experts: t -> (ehalf, c = K-chunk of 32, sq) ----
        {
            const int rem = t & 511;
            const int c   = rem >> 5;      // 0..15 (HIGH bits)
            const int sq  = rem & 31;      // s-quad (LOW bits -> coalesced)
            const float* Bp = Bin_l + (size_t)esel * DSZ * SSZ + sq * 4;
            const int d0 = c * 32;
            f32x4 a0 = {0.f,0.f,0.f,0.f}, a1 = a0;
            #pragma unroll 8
            for (int d = 0; d < 32; d += 2) {
                a0 += *(const f32x4*)(Bp + (size_t)(d0 + d) * SSZ) * h_s[d0 + d];
                a1 += *(const f32x4*)(Bp + (size_t)(d0 + d + 1) * SSZ) * h_s[d0 + d + 1];
            }
            part4[(ehalf * 16 + c) * 32 + sq] = a0 + a1;
        }
        __syncthreads();                                        // b4

        // combine + decay -> snew_s (+ selected out_states); passthrough others
        if (t < TOPK * SSZ) {
            const int k = t >> 7, s = t & 127;
            const int e = k ? i1 : i0;
            float sum = 0.f;
            #pragma unroll
            for (int c = 0; c < 16; ++c) sum += part[(k * 16 + c) * 128 + s];
            const float a = A_l[e * SSZ + s];
            const float decay = 1.f / (1.f + expf(-a));
            const float sn = decay * st_l[((size_t)e * BSZ + b) * SSZ + s] + sum;
            snew_s[k][s] = sn;
            os_l[((size_t)e * BSZ + b) * SSZ + s] = sn;
        }
        {   // passthrough unselected experts (no dependency on snew_s)
            const int e = t >> 7, s = t & 127;
            if (e != i0 && e != i1)
                os_l[((size_t)e * BSZ + b) * SSZ + s] = st_l[((size_t)e * BSZ + b) * SSZ + s];
        }
        __syncthreads();                                        // b5

        // ---- y partials, both experts: t -> (ehalf, sc = S-chunk of 32, dq) ----
        {
            const int rem = t & 511;
            const int sc  = rem >> 7;      // 0..3 (HIGH bits)
            const int dq  = rem & 127;     // d-quad (LOW bits -> coalesced)
            const float* Cp = Cou_l + (size_t)esel * SSZ * DSZ + dq * 4;
            const float* sp = snew_s[ehalf];
            const int s0 = sc * 32;
            f32x4 a0 = {0.f,0.f,0.f,0.f}, a1 = a0;
            #pragma unroll 8
            for (int s = 0; s < 32; s += 2) {
                a0 += *(const f32x4*)(Cp + (size_t)(s0 + s) * DSZ) * sp[s0 + s];
                a1 += *(const f32x4*)(Cp + (size_t)(s0 + s + 1) * DSZ) * sp[s0 + s + 1];
            }
            part4[(ehalf * 4 + sc) * 128 + dq] = a0 + a1;
        }
        __syncthreads();                                        // b6

        // h update: h_new = h + g0*y0 + g1*y1 (b1 of next layer fences h_s)
        if (t < DSZ) {
            const float hd = h_s[t];
            float y0 = hd * Dsk_l[i0 * DSZ + t];
            float y1 = hd * Dsk_l[i1 * DSZ + t];
            #pragma unroll
            for (int c = 0; c < 4; ++c) {
                y0 += part[c * 512 + t];
                y1 += part[(4 + c) * 512 + t];
            }
            h_s[t] = hd + g0 * y0 + g1 * y1;
        }
    }

    __syncthreads();   // h_s final ready
    // ---- q = h @ Wq + bq -> q_s (stays in LDS) ----
    {
        const int chunk = t >> 7;        // 0..7, dd-chunk of 64
        const int dquad = t & 127;
        const int dd0 = chunk * 64;
        f32x4 acc4 = {0.f, 0.f, 0.f, 0.f};
        #pragma unroll 8
        for (int i = 0; i < 64; ++i)
            acc4 += *(const f32x4*)(Wq + (size_t)(dd0 + i) * DSZ + dquad * 4) * h_s[dd0 + i];
        part4[chunk * 128 + dquad] = acc4;
    }
    __syncthreads();
    if (t < DSZ) {
        float qv = bq[t];
        #pragma unroll
        for (int c = 0; c < 8; ++c) qv += part[c * 512 + t];
        q_s[t] = qv;
    }
    __syncthreads();

    // ---- logits: wave w streams rows w*64 .. w*64+63 of node_emb[b] ----
    {
        const f32x4 q0 = ((const f32x4*)q_s)[lane];
        const f32x4 q1 = ((const f32x4*)q_s)[lane + 64];
        const float scale = 0.04419417382415922f;  // 1/sqrt(512)
        const int n0 = wave * 64;
        for (int i = 0; i < 64; i += 2) {
            const f32x4* r0 = (const f32x4*)(node_emb + ((size_t)b * NSZ + n0 + i) * DSZ);
            const f32x4* r1 = (const f32x4*)(node_emb + ((size_t)b * NSZ + n0 + i + 1) * DSZ);
            const f32x4 a0 = __builtin_nontemporal_load(r0 + lane);
            const f32x4 a1 = __builtin_nontemporal_load(r0 + lane + 64);
            const f32x4 c0 = __builtin_nontemporal_load(r1 + lane);
            const f32x4 c1 = __builtin_nontemporal_load(r1 + lane + 64);
            float d0 = a0.x*q0.x + a0.y*q0.y + a0.z*q0.z + a0.w*q0.w
                     + a1.x*q1.x + a1.y*q1.y + a1.z*q1.z + a1.w*q1.w;
            float d1 = c0.x*q0.x + c0.y*q0.y + c0.z*q0.z + c0.w*q0.w
                     + c1.x*q1.x + c1.y*q1.y + c1.z*q1.z + c1.w*q1.w;
            #pragma unroll
            for (int off = 32; off; off >>= 1) {
                d0 += __shfl_down(d0, off, 64);
                d1 += __shfl_down(d1, off, 64);
            }
            if (lane == 0) {
                out_logits[b * NSZ + n0 + i]     = d0 * scale;
                out_logits[b * NSZ + n0 + i + 1] = d1 * scale;
            }
        }
    }
}

// ---------------- lb_loss finisher ----------------
__global__ void loss_kernel(const float* __restrict__ acc, float* __restrict__ out)
{
    if (threadIdx.x == 0) {
        float lb = 0.f;
        for (int l = 0; l < LNUM; ++l)
            for (int e = 0; e < ENUM; ++e) {
                const float mp = acc[(l * 2 + 0) * ENUM + e] * (1.0f / BSZ);
                const float ms = acc[(l * 2 + 1) * ENUM + e] * (1.0f / BSZ);
                lb += (float)ENUM * mp * ms;
            }
        out[0] = lb;
    }
}

extern "C" void kernel_launch(void* const* d_in, const int* in_sizes, int n_in,
                              void* d_out, int out_size, void* d_ws, size_t ws_size,
                              hipStream_t stream) {
    const float* token    = (const float*)d_in[0];  // B,1,D
    const float* node_emb = (const float*)d_in[1];  // B,N,D
    const float* states   = (const float*)d_in[2];  // L,E,B,DS
    const float* Wg       = (const float*)d_in[3];  // L,D,E
    const float* bg       = (const float*)d_in[4];  // L,E
    const float* A        = (const float*)d_in[5];  // L,E,DS
    const float* Bin      = (const float*)d_in[6];  // L,E,D,DS
    const float* Cout     = (const float*)d_in[7];  // L,E,DS,D
    const float* Dsk      = (const float*)d_in[8];  // L,E,D
    const float* Wq       = (const float*)d_in[9];  // D,D
    const float* bq       = (const float*)d_in[10]; // D

    float* out_logits = (float*)d_out;                                  // B*N
    float* out_states = out_logits + (size_t)BSZ * NSZ;                 // L*E*B*DS
    float* out_loss   = out_states + (size_t)LNUM * ENUM * BSZ * SSZ;   // 1

    float* ws_acc = (float*)d_ws;   // 48 floats

    (void)hipMemsetAsync(ws_acc, 0, sizeof(float) * LNUM * 16, stream);

    mega_kernel<<<BSZ, 1024, 0, stream>>>(
        token, node_emb, states, Wg, bg, A, Bin, Cout, Dsk, Wq, bq,
        out_logits, out_states, ws_acc);

    loss_kernel<<<1, 64, 0, stream>>>(ws_acc, out_loss);
}

// Round 15
// 161.406 us; speedup vs baseline: 1.4430x; 1.0306x over previous
//
#include <hip/hip_runtime.h>
#include <math.h>

#define LNUM 3
#define ENUM 8
#define TOPK 2
#define BSZ 256
#define NSZ 1024
#define DSZ 512
#define SSZ 128   // DS

typedef float f32x4 __attribute__((ext_vector_type(4)));

// ---------------- mega kernel: 3 layers + q + logits, block b owns token b ----------------
// grid = BSZ blocks, 1024 threads (16 waves). h lives in LDS across layers.
// Experts sequential (R10/R14: beats concurrent). LDS-partial combines with
// column idx in LOW lane bits (R12: K-in-low-bits destroys coalescing).
// out_states writes DEFERRED to post-chain (kept in LDS) so chain phases carry
// no latency-exposed stores and L2 stays weight-resident.
__global__ __launch_bounds__(1024, 2) void mega_kernel(
    const float* __restrict__ token,   // [B][D]
    const float* __restrict__ node_emb,// [B][N][D]
    const float* __restrict__ states,  // [L][E][B][DS]
    const float* __restrict__ Wg,      // [L][D][E]
    const float* __restrict__ bg,      // [L][E]
    const float* __restrict__ A,       // [L][E][DS]
    const float* __restrict__ Bin,     // [L][E][D][DS]
    const float* __restrict__ Cout,    // [L][E][DS][D]
    const float* __restrict__ Dsk,     // [L][E][D]
    const float* __restrict__ Wq,      // [D][D]
    const float* __restrict__ bq,      // [D]
    float* __restrict__ out_logits,    // [B][N]
    float* __restrict__ out_states,    // [L][E][B][DS]
    float* __restrict__ acc)           // [L][2][E] (probs, sel) — pre-zeroed
{
    const int b = blockIdx.x;
    const int t = threadIdx.x;
    const int wave = t >> 6;
    const int lane = t & 63;

    __shared__ float h_s[DSZ];
    __shared__ float yacc_s[DSZ];      // also q_s in the logits phase
    __shared__ float snew_all[LNUM][TOPK][SSZ];   // parked for deferred writes
    __shared__ int   sel_all[LNUM][TOPK];
    __shared__ float logit_s[ENUM];
    __shared__ f32x4 part4[1024];      // 16 KB scratch, reused every phase
    float* part = (float*)part4;

    if (t < 128) ((f32x4*)h_s)[t] = ((const f32x4*)(token + (size_t)b * DSZ))[t];

    for (int l = 0; l < LNUM; ++l) {
        const float* Wg_l  = Wg  + (size_t)l * DSZ * ENUM;
        const float* bg_l  = bg  + (size_t)l * ENUM;
        const float* A_l   = A   + (size_t)l * ENUM * SSZ;
        const float* Bin_l = Bin + (size_t)l * ENUM * DSZ * SSZ;
        const float* Cou_l = Cout+ (size_t)l * ENUM * SSZ * DSZ;
        const float* Dsk_l = Dsk + (size_t)l * ENUM * DSZ;
        const float* st_l  = states + (size_t)l * ENUM * BSZ * SSZ;

        // stage Wg[l] (16 KB) into part; also fences h_s (init load / l-1 update)
        __syncthreads();
        part4[t] = ((const f32x4*)Wg_l)[t];
        __syncthreads();

        // gating logits: wave w computes expert w from staged Wg
        if (wave < ENUM) {
            float p = 0.f;
            #pragma unroll
            for (int i = 0; i < 8; ++i) {
                const int d = lane + i * 64;
                p = fmaf(h_s[d], part[d * ENUM + wave], p);
            }
            for (int off = 32; off; off >>= 1) p += __shfl_down(p, off, 64);
            if (lane == 0) logit_s[wave] = p + bg_l[wave];
        }
        __syncthreads();

        // softmax + top2, redundantly per thread (identical results)
        float probs[ENUM];
        float mx = logit_s[0];
        for (int e = 1; e < ENUM; ++e) mx = fmaxf(mx, logit_s[e]);
        float ssum = 0.f;
        for (int e = 0; e < ENUM; ++e) { probs[e] = expf(logit_s[e] - mx); ssum += probs[e]; }
        const float sinv = 1.f / ssum;
        for (int e = 0; e < ENUM; ++e) probs[e] *= sinv;

        int i0 = 0;
        for (int e = 1; e < ENUM; ++e) if (probs[e] > probs[i0]) i0 = e;
        int i1 = -1;
        for (int e = 0; e < ENUM; ++e) {
            if (e == i0) continue;
            if (i1 < 0 || probs[e] > probs[i1]) i1 = e;
        }
        float g0 = probs[i0], g1 = probs[i1];
        const float ginv = 1.f / (g0 + g1);
        g0 *= ginv; g1 *= ginv;

        if (t < ENUM) {
            atomicAdd(&acc[(l * 2 + 0) * ENUM + t], probs[t]);
            atomicAdd(&acc[(l * 2 + 1) * ENUM + t], (t == i0 || t == i1) ? 1.0f : 0.0f);
        }
        if (t == 0) { sel_all[l][0] = i0; sel_all[l][1] = i1; }

        // ---- s_new: experts sequentially, all 1024 threads each ----
        #pragma unroll
        for (int k = 0; k < TOPK; ++k) {
            const int e = k ? i1 : i0;
            {
                const int c  = t >> 5;     // 0..31, K-chunk of 16 (HIGH bits)
                const int sq = t & 31;     // s-quad (LOW bits -> coalesced)
                const float* Bp = Bin_l + (size_t)e * DSZ * SSZ + sq * 4;
                const int d0 = c * 16;
                f32x4 a0 = {0.f,0.f,0.f,0.f}, a1 = a0;
                #pragma unroll
                for (int d = 0; d < 16; d += 2) {
                    a0 += *(const f32x4*)(Bp + (size_t)(d0 + d) * SSZ) * h_s[d0 + d];
                    a1 += *(const f32x4*)(Bp + (size_t)(d0 + d + 1) * SSZ) * h_s[d0 + d + 1];
                }
                part4[c * 32 + sq] = a0 + a1;
            }
            __syncthreads();
            if (t < SSZ) {
                float sum = 0.f;
                #pragma unroll
                for (int c = 0; c < 32; ++c) sum += part[c * 128 + t];
                const float a = A_l[e * SSZ + t];
                const float decay = 1.f / (1.f + expf(-a));
                snew_all[l][k][t] = decay * st_l[((size_t)e * BSZ + b) * SSZ + t] + sum;
            }
            __syncthreads();
        }

        // ---- y: experts sequentially, all 1024 threads each ----
        #pragma unroll
        for (int k = 0; k < TOPK; ++k) {
            const int e = k ? i1 : i0;
            const float g = k ? g1 : g0;
            {
                const int sc = t >> 7;     // 0..7, S-chunk of 16 (HIGH bits)
                const int dq = t & 127;    // d-quad (LOW bits -> coalesced)
                const float* Cp = Cou_l + (size_t)e * SSZ * DSZ + dq * 4;
                const float* sp = snew_all[l][k];
                const int s0 = sc * 16;
                f32x4 a0 = {0.f,0.f,0.f,0.f}, a1 = a0;
                #pragma unroll
                for (int s = 0; s < 16; s += 2) {
                    a0 += *(const f32x4*)(Cp + (size_t)(s0 + s) * DSZ) * sp[s0 + s];
                    a1 += *(const f32x4*)(Cp + (size_t)(s0 + s + 1) * DSZ) * sp[s0 + s + 1];
                }
                part4[sc * 128 + dq] = a0 + a1;
            }
            __syncthreads();
            if (t < DSZ) {
                float yk = 0.f;
                #pragma unroll
                for (int sc = 0; sc < 8; ++sc) yk += part[sc * 512 + t];
                const float hd = h_s[t];
                yk = g * (yk + hd * Dsk_l[e * DSZ + t]);
                if (k == 0) yacc_s[t] = yk;
                else        h_s[t] = hd + yacc_s[t] + yk;
            }
            __syncthreads();
        }
    }

    // ---- q = h @ Wq + bq -> yacc_s (stays in LDS) ----
    {
        const int chunk = t >> 7;        // 0..7, dd-chunk of 64
        const int dquad = t & 127;
        const int dd0 = chunk * 64;
        f32x4 acc4 = {0.f, 0.f, 0.f, 0.f};
        #pragma unroll 8
        for (int i = 0; i < 64; ++i)
            acc4 += *(const f32x4*)(Wq + (size_t)(dd0 + i) * DSZ + dquad * 4) * h_s[dd0 + i];
        part4[chunk * 128 + dquad] = acc4;
    }
    __syncthreads();
    if (t < DSZ) {
        float qv = bq[t];
        #pragma unroll
        for (int c = 0; c < 8; ++c) qv += part[c * 512 + t];
        yacc_s[t] = qv;
    }
    __syncthreads();

    // ---- deferred out_states writes: 3 layers x 8 experts x 128, nontemporal ----
    // overlaps with the logits HBM stream issue window; off the chain critical path
    for (int idx = t; idx < LNUM * ENUM * SSZ; idx += 1024) {
        const int l = idx >> 10;
        const int e = (idx >> 7) & 7;
        const int s = idx & 127;
        const size_t off = ((size_t)l * ENUM + e) * BSZ * SSZ + (size_t)b * SSZ + s;
        float v;
        if (e == sel_all[l][0])      v = snew_all[l][0][s];
        else if (e == sel_all[l][1]) v = snew_all[l][1][s];
        else                         v = __builtin_nontemporal_load(states + off);
        __builtin_nontemporal_store(v, out_states + off);
    }

    // ---- logits: wave w streams rows w*64 .. w*64+63 of node_emb[b] ----
    {
        const f32x4 q0 = ((const f32x4*)yacc_s)[lane];
        const f32x4 q1 = ((const f32x4*)yacc_s)[lane + 64];
        const float scale = 0.04419417382415922f;  // 1/sqrt(512)
        const int n0 = wave * 64;
        for (int i = 0; i < 64; i += 2) {
            const f32x4* r0 = (const f32x4*)(node_emb + ((size_t)b * NSZ + n0 + i) * DSZ);
            const f32x4* r1 = (const f32x4*)(node_emb + ((size_t)b * NSZ + n0 + i + 1) * DSZ);
            const f32x4 a0 = __builtin_nontemporal_load(r0 + lane);
            const f32x4 a1 = __builtin_nontemporal_load(r0 + lane + 64);
            const f32x4 c0 = __builtin_nontemporal_load(r1 + lane);
            const f32x4 c1 = __builtin_nontemporal_load(r1 + lane + 64);
            float d0 = a0.x*q0.x + a0.y*q0.y + a0.z*q0.z + a0.w*q0.w
                     + a1.x*q1.x + a1.y*q1.y + a1.z*q1.z + a1.w*q1.w;
            float d1 = c0.x*q0.x + c0.y*q0.y + c0.z*q0.z + c0.w*q0.w
                     + c1.x*q1.x + c1.y*q1.y + c1.z*q1.z + c1.w*q1.w;
            #pragma unroll
            for (int off = 32; off; off >>= 1) {
                d0 += __shfl_down(d0, off, 64);
                d1 += __shfl_down(d1, off, 64);
            }
            if (lane == 0) {
                out_logits[b * NSZ + n0 + i]     = d0 * scale;
                out_logits[b * NSZ + n0 + i + 1] = d1 * scale;
            }
        }
    }
}

// ---------------- lb_loss finisher ----------------
__global__ void loss_kernel(const float* __restrict__ acc, float* __restrict__ out)
{
    if (threadIdx.x == 0) {
        float lb = 0.f;
        for (int l = 0; l < LNUM; ++l)
            for (int e = 0; e < ENUM; ++e) {
                const float mp = acc[(l * 2 + 0) * ENUM + e] * (1.0f / BSZ);
                const float ms = acc[(l * 2 + 1) * ENUM + e] * (1.0f / BSZ);
                lb += (float)ENUM * mp * ms;
            }
        out[0] = lb;
    }
}

extern "C" void kernel_launch(void* const* d_in, const int* in_sizes, int n_in,
                              void* d_out, int out_size, void* d_ws, size_t ws_size,
                              hipStream_t stream) {
    const float* token    = (const float*)d_in[0];  // B,1,D
    const float* node_emb = (const float*)d_in[1];  // B,N,D
    const float* states   = (const float*)d_in[2];  // L,E,B,DS
    const float* Wg       = (const float*)d_in[3];  // L,D,E
    const float* bg       = (const float*)d_in[4];  // L,E
    const float* A        = (const float*)d_in[5];  // L,E,DS
    const float* Bin      = (const float*)d_in[6];  // L,E,D,DS
    const float* Cout     = (const float*)d_in[7];  // L,E,DS,D
    const float* Dsk      = (const float*)d_in[8];  // L,E,D
    const float* Wq       = (const float*)d_in[9];  // D,D
    const float* bq       = (const float*)d_in[10]; // D

    float* out_logits = (float*)d_out;                                  // B*N
    float* out_states = out_logits + (size_t)BSZ * NSZ;                 // L*E*B*DS
    float* out_loss   = out_states + (size_t)LNUM * ENUM * BSZ * SSZ;   // 1

    float* ws_acc = (float*)d_ws;   // 48 floats

    (void)hipMemsetAsync(ws_acc, 0, sizeof(float) * LNUM * 16, stream);

    mega_kernel<<<BSZ, 1024, 0, stream>>>(
        token, node_emb, states, Wg, bg, A, Bin, Cout, Dsk, Wq, bq,
        out_logits, out_states, ws_acc);

    loss_kernel<<<1, 64, 0, stream>>>(ws_acc, out_loss);
}